// Round 3
// baseline (579.068 us; speedup 1.0000x reference)
//
#include <hip/hip_runtime.h>
#include <hip/hip_bf16.h>
#include <stdint.h>

#define B_SZ 32
#define S_SZ 2048
#define H_SZ 1024
#define K_SZ 1024
#define M_SZ (B_SZ * S_SZ)   // 65536 rows of the big GEMM

typedef __attribute__((ext_vector_type(8))) short bf16x8;   // 8 bf16 = 4 VGPRs (MFMA A/B frag)
typedef __attribute__((ext_vector_type(4))) float f32x4;    // MFMA C/D frag

// ---- helpers ----------------------------------------------------------------

__device__ __forceinline__ short f2bf_rne(float f) {
    uint32_t u = __builtin_bit_cast(uint32_t, f);
    u += 0x7fffu + ((u >> 16) & 1u);   // round-to-nearest-even
    return (short)(u >> 16);
}

__device__ __forceinline__ float bf2f(unsigned short u) {
    return __builtin_bit_cast(float, (uint32_t)u << 16);
}

__device__ __forceinline__ float fast_tanh(float x) {
    // tanh(x) = 1 - 2/(exp(2x)+1); exact limits at +-inf, ~1e-6 rel err.
    float ex = __expf(2.0f * x);
    return 1.0f - 2.0f / (ex + 1.0f);
}

// ---- fp32 -> bf16 conversion (8 elems/thread, grid-stride) ------------------

__global__ void cvt_bf16_k(const float* __restrict__ in,
                           __hip_bfloat16* __restrict__ out, int n8) {
    int idx = blockIdx.x * blockDim.x + threadIdx.x;
    int stride = gridDim.x * blockDim.x;
    for (int i = idx; i < n8; i += stride) {
        const float4* p = (const float4*)in + (size_t)i * 2;
        float4 a = p[0], b = p[1];
        bf16x8 r;
        r[0] = f2bf_rne(a.x); r[1] = f2bf_rne(a.y);
        r[2] = f2bf_rne(a.z); r[3] = f2bf_rne(a.w);
        r[4] = f2bf_rne(b.x); r[5] = f2bf_rne(b.y);
        r[6] = f2bf_rne(b.z); r[7] = f2bf_rne(b.w);
        ((bf16x8*)out)[i] = r;
    }
}

// ---- dec_proj[b][k] = dot(dec[b,:], Wb[k,:]) + Wb_b[k] + Wc_b[k] ------------

__global__ __launch_bounds__(256) void decproj_k(
    const float* __restrict__ ds, const float* __restrict__ Wb,
    const float* __restrict__ Wb_b, const float* __restrict__ Wc_b,
    float* __restrict__ dp) {
    int g = blockIdx.x * 4 + (threadIdx.x >> 6);   // wave id = output id
    int lane = threadIdx.x & 63;
    int b = g >> 10;
    int k = g & 1023;
    const float4* wrow = (const float4*)(Wb + (size_t)k * H_SZ);
    const float4* xrow = (const float4*)(ds + (size_t)b * H_SZ);
    float sum = 0.f;
#pragma unroll
    for (int it = 0; it < 4; it++) {
        float4 w = wrow[lane + it * 64];
        float4 x = xrow[lane + it * 64];
        sum += w.x * x.x + w.y * x.y + w.z * x.z + w.w * x.w;
    }
#pragma unroll
    for (int off = 1; off < 64; off <<= 1) sum += __shfl_xor(sum, off, 64);
    if (lane == 0) dp[g] = sum + Wb_b[k] + Wc_b[k];
}

// ============================================================================
// 256x256-tile GEMM, exact m201 8-phase skeleton (verified 824 cyc/phase):
//   [ds_read frags for THIS phase] [stage 1 half-tile]
//   s_barrier ; s_waitcnt lgkmcnt(0) ; setprio(1) ; 16 MFMA ; setprio(0) ;
//   [ph3 only: counted s_waitcnt vmcnt(4)] ; s_barrier
// NO sched_barrier(0) anywhere (m141 regression mechanism — this was R1's
// 1931-cyc/phase mistake). Reads issued BEFORE bar1 so their lgkm latency
// overlaps the barrier wait; lgkm(0) drain after bar1 is then ~free.
// Rule #18 does not apply: frag reads are C++ loads, the compiler tracks
// the MFMA dependency itself.
//
// Geometry: BM=BN=256, BK=64, 8 waves (2Mx4N), 512 thr, LDS 128 KiB (2 dbuf),
// 1 block/CU, 2 waves/SIMD (128 VGPR + 128 AGPR acc).
//
// Staging (verified twice): ph0 A0(t+1)->Anxt, ph1 A1(t+1), ph2 B0(t+2)->Bcur,
// ph3 B1(t+2). In-flight at ph3: B(t+1)x4 + A(t+1)x4 + B(t+2)x4 = 12;
// vmcnt(4) => B(t+1),A(t+1) landed, B(t+2) stays in flight. Race-freedom:
// any staged region's last reader drained its lgkm >=2 barriers before the
// staging wave can issue the overwrite.
//
// LDS swizzle (T2, rule #21): store byte L of a [.][64]bf16 row at
// L ^ ((row&7)<<4); global_load_lds dest LINEAR, source inverse-swizzled,
// ds_read applies the same involution. Verified: bank conflicts 1.68e7 -> 0.
// ============================================================================

__device__ __forceinline__ void stage2(const __hip_bfloat16* __restrict__ srcRowBase,
                                       unsigned char* ldsHt, int k0,
                                       size_t laneOff, int ldsLane) {
#pragma unroll
    for (int inst = 0; inst < 2; inst++) {
        const char* g = (const char*)srcRowBase + (size_t)k0 * 2 + laneOff +
                        (size_t)inst * (64 * H_SZ * 2);
        __builtin_amdgcn_global_load_lds(
            (const __attribute__((address_space(1))) void*)g,
            (__attribute__((address_space(3))) void*)(ldsHt + inst * 8192 + ldsLane),
            16, 0, 0);
    }
}

__device__ __forceinline__ void read_afr(bf16x8 (&afr)[2][2], const unsigned char* Abuf,
                                         int aRowB, int phOff, int kOff0, int kOff1) {
#pragma unroll
    for (int i = 0; i < 2; ++i) {
        afr[i][0] = *(const bf16x8*)(Abuf + aRowB + phOff + i * 2048 + kOff0);
        afr[i][1] = *(const bf16x8*)(Abuf + aRowB + phOff + i * 2048 + kOff1);
    }
}

__device__ __forceinline__ void read_bfr(bf16x8 (&bfr)[4][2], const unsigned char* Bbuf,
                                         int bRowB, int kOff0, int kOff1) {
#pragma unroll
    for (int n = 0; n < 4; ++n) {
        bfr[n][0] = *(const bf16x8*)(Bbuf + bRowB + n * 2048 + kOff0);
        bfr[n][1] = *(const bf16x8*)(Bbuf + bRowB + n * 2048 + kOff1);
    }
}

// VM: 4 = steady counted wait, 0 = drain (tile 14), -1 = none (last tile)
template <int VM, bool SA, bool SB>
__device__ __forceinline__ void tile_run(
    const __hip_bfloat16* __restrict__ AgR, const __hip_bfloat16* __restrict__ BgR,
    const unsigned char* Acur, unsigned char* BcurW, unsigned char* Anxt,
    int kA, int kB, size_t laneOff, int ldsLane,
    int aRowB, int bRowB, int kOff0, int kOff1,
    f32x4 (&acc)[8][4])
{
    bf16x8 bfr[4][2];   // B-frags for this tile live across all 4 phases
#pragma unroll
    for (int ph = 0; ph < 4; ++ph) {
        // ---- pre-barrier window: issue this phase's reads + one stage ----
        if (ph == 0) read_bfr(bfr, BcurW, bRowB, kOff0, kOff1);
        bf16x8 afr[2][2];
        read_afr(afr, Acur, aRowB, ph * 4096, kOff0, kOff1);
        if (SA && ph == 0) stage2(AgR,                Anxt,          kA, laneOff, ldsLane);
        if (SA && ph == 1) stage2(AgR + 128 * H_SZ,   Anxt + 16384,  kA, laneOff, ldsLane);
        if (SB && ph == 2) stage2(BgR,                BcurW,         kB, laneOff, ldsLane);
        if (SB && ph == 3) stage2(BgR + 128 * H_SZ,   BcurW + 16384, kB, laneOff, ldsLane);
        // ---- barrier; drain lgkm (overlapped with barrier wait); MFMA ----
        __builtin_amdgcn_s_barrier();
        asm volatile("s_waitcnt lgkmcnt(0)" ::: "memory");
        __builtin_amdgcn_s_setprio(1);
#pragma unroll
        for (int i = 0; i < 2; ++i)
#pragma unroll
            for (int ks = 0; ks < 2; ++ks)
#pragma unroll
                for (int n = 0; n < 4; ++n)
                    acc[ph * 2 + i][n] = __builtin_amdgcn_mfma_f32_16x16x32_bf16(
                        afr[i][ks], bfr[n][ks], acc[ph * 2 + i][n], 0, 0, 0);
        __builtin_amdgcn_s_setprio(0);
        if (ph == 3 && VM == 4) asm volatile("s_waitcnt vmcnt(4)" ::: "memory");
        if (ph == 3 && VM == 0) asm volatile("s_waitcnt vmcnt(0)" ::: "memory");
        __builtin_amdgcn_s_barrier();
    }
}

__global__ __launch_bounds__(512, 2) void gemm256_scores_k(
    const __hip_bfloat16* __restrict__ Ag, const __hip_bfloat16* __restrict__ Bg,
    const float* __restrict__ decp, const float* __restrict__ Wa,
    float* __restrict__ sp)
{
    __shared__ __align__(16) unsigned char lds[131072];
    const int t = threadIdx.x;
    const int wave = t >> 6, lane = t & 63;
    const int wr = wave >> 2, wc = wave & 3;     // 2x4 waves over 256x256
    const int quad = lane >> 4, l15 = lane & 15;

    // XCD swizzle: 1024 blocks = 256 rowBlks x 4 colBlks; a rowBlk's 4 colBlks
    // land on the same XCD at consecutive per-XCD slots -> A-panel L2 reuse.
    const int id = blockIdx.x;
    const int colBlk = (id >> 3) & 3;
    const int rowBlk = ((id >> 5) << 3) | (id & 7);
    const int row0 = rowBlk * 256, col0 = colBlk * 256;  // 256|2048: one batch

    const int swz = (l15 & 7) << 4;              // row&7 == l15&7 for all frags
    const int aRowB = (wr * 128 + l15) * 128;
    const int bRowB = (wc * 64 + l15) * 128;
    const int kOff0 = (quad * 16) ^ swz;
    const int kOff1 = (64 + quad * 16) ^ swz;

    // staging per-lane constants
    const size_t laneOff = (size_t)(t >> 3) * (H_SZ * 2) +
                           ((((t & 7) ^ ((t >> 3) & 7)) << 4));
    const int ldsLane = (t >> 6) << 10;
    const __hip_bfloat16* AgR = Ag + (size_t)row0 * H_SZ;
    const __hip_bfloat16* BgR = Bg + (size_t)col0 * H_SZ;

    f32x4 acc[8][4];
#pragma unroll
    for (int i = 0; i < 8; i++)
#pragma unroll
        for (int j = 0; j < 4; j++) acc[i][j] = f32x4{0.f, 0.f, 0.f, 0.f};

    unsigned char* A0l = lds;                    // buf0: A [0,32K) B [32K,64K)
    unsigned char* B0l = lds + 32768;
    unsigned char* A1l = lds + 65536;            // buf1: A [64K,96K) B [96K,128K)
    unsigned char* B1l = lds + 98304;

    // prologue: tile0 fully + tile1's B; vmcnt(4) leaves tile1's B in flight
    stage2(BgR,                B0l,          0, laneOff, ldsLane);
    stage2(BgR + 128 * H_SZ,   B0l + 16384,  0, laneOff, ldsLane);
    stage2(AgR,                A0l,          0, laneOff, ldsLane);
    stage2(AgR + 128 * H_SZ,   A0l + 16384,  0, laneOff, ldsLane);
    stage2(BgR,                B1l,         64, laneOff, ldsLane);
    stage2(BgR + 128 * H_SZ,   B1l + 16384, 64, laneOff, ldsLane);
    asm volatile("s_waitcnt vmcnt(4)" ::: "memory");
    __builtin_amdgcn_s_barrier();

    // 16 K-tiles of 64: steady tiles 0..13, then drain tiles 14 and 15
#pragma unroll 2
    for (int tt = 0; tt < 14; ++tt) {
        unsigned char* Ac = (tt & 1) ? A1l : A0l;
        unsigned char* Bc = (tt & 1) ? B1l : B0l;
        unsigned char* An = (tt & 1) ? A0l : A1l;
        tile_run<4, true, true>(AgR, BgR, Ac, Bc, An,
                                (tt + 1) * 64, (tt + 2) * 64, laneOff, ldsLane,
                                aRowB, bRowB, kOff0, kOff1, acc);
    }
    tile_run<0, true, false>(AgR, BgR, A0l, B0l, A1l,
                             15 * 64, 0, laneOff, ldsLane,
                             aRowB, bRowB, kOff0, kOff1, acc);
    tile_run<-1, false, false>(AgR, BgR, A1l, B1l, A0l,
                               0, 0, laneOff, ldsLane,
                               aRowB, bRowB, kOff0, kOff1, acc);

    // fused epilogue: partial_m = sum_n Wa[n]*tanh(C[m][n]+decp[b][n])
    const int b = row0 >> 11;
    float wa_j[4], dp_j[4];
#pragma unroll
    for (int n = 0; n < 4; ++n) {
        int c = col0 + wc * 64 + n * 16 + l15;
        wa_j[n] = Wa[c];
        dp_j[n] = decp[b * K_SZ + c];
    }
    const int slotIdx = colBlk * 4 + wc;   // 16 partial slots per row
#pragma unroll
    for (int m = 0; m < 8; ++m) {
#pragma unroll
        for (int r = 0; r < 4; ++r) {
            float tsum = 0.f;
#pragma unroll
            for (int n = 0; n < 4; ++n)
                tsum += wa_j[n] * fast_tanh(acc[m][n][r] + dp_j[n]);
            // C/D layout: row=(lane>>4)*4+reg, col=lane&15 -> reduce 16 cols
#pragma unroll
            for (int off = 1; off < 16; off <<= 1) tsum += __shfl_xor(tsum, off, 64);
            if (l15 == 0) {
                int mrow = row0 + wr * 128 + m * 16 + quad * 4 + r;
                sp[(size_t)slotIdx * M_SZ + mrow] = tsum;
            }
        }
    }
}

// ---- legacy 128x128 GEMM (fp32-A fallback when ws is small) ----------------

template <bool AF32>
__global__ __launch_bounds__(256) void gemm_scores_k(
    const void* __restrict__ Aptr, const __hip_bfloat16* __restrict__ Bw,
    const float* __restrict__ decp, const float* __restrict__ Wa,
    float* __restrict__ sp) {
    constexpr int ABYTES = AF32 ? 128 * 32 * 4 : 128 * 32 * 2;
    __shared__ __align__(16) unsigned char AsmRaw[ABYTES];
    __shared__ __align__(16) unsigned char BsmRaw[128 * 32 * 2];

    const int t = threadIdx.x;
    const int wave = t >> 6;
    const int lane = t & 63;
    const int wm = wave >> 1, wn = wave & 1;
    const int quad = lane >> 4;
    const int l15 = lane & 15;

    const int id = blockIdx.x;
    const int colBlk = (id >> 3) & 7;
    const int rowBlk = ((id >> 6) << 3) | (id & 7);
    const int row0 = rowBlk * 128;
    const int col0 = colBlk * 128;
    const int b = row0 >> 11;

    f32x4 acc[4][4];
#pragma unroll
    for (int i = 0; i < 4; i++)
#pragma unroll
        for (int j = 0; j < 4; j++) acc[i][j] = f32x4{0.f, 0.f, 0.f, 0.f};

    const __hip_bfloat16* Ab = (const __hip_bfloat16*)Aptr;
    const float* Af = (const float*)Aptr;

    for (int k0 = 0; k0 < H_SZ; k0 += 32) {
        if constexpr (AF32) {
#pragma unroll
            for (int inst = 0; inst < 4; inst++) {
                int slot = inst * 256 + t;
                int r = slot >> 3, c4 = slot & 7;
                const float* g = Af + (size_t)(row0 + r) * H_SZ + k0 + c4 * 4;
                __builtin_amdgcn_global_load_lds(
                    (const __attribute__((address_space(1))) void*)g,
                    (__attribute__((address_space(3))) void*)(AsmRaw + inst * 4096 + wave * 1024),
                    16, 0, 0);
            }
        } else {
#pragma unroll
            for (int inst = 0; inst < 2; inst++) {
                int slot = inst * 256 + t;
                int r = slot >> 2, c8 = slot & 3;
                const __hip_bfloat16* g = Ab + (size_t)(row0 + r) * H_SZ + k0 + c8 * 8;
                __builtin_amdgcn_global_load_lds(
                    (const __attribute__((address_space(1))) void*)g,
                    (__attribute__((address_space(3))) void*)(AsmRaw + inst * 4096 + wave * 1024),
                    16, 0, 0);
            }
        }
#pragma unroll
        for (int inst = 0; inst < 2; inst++) {
            int slot = inst * 256 + t;
            int r = slot >> 2, c8 = slot & 3;
            const __hip_bfloat16* g = Bw + (size_t)(col0 + r) * H_SZ + k0 + c8 * 8;
            __builtin_amdgcn_global_load_lds(
                (const __attribute__((address_space(1))) void*)g,
                (__attribute__((address_space(3))) void*)(BsmRaw + inst * 4096 + wave * 1024),
                16, 0, 0);
        }
        __syncthreads();

        bf16x8 afr[4], bfr[4];
#pragma unroll
        for (int i = 0; i < 4; i++) {
            int r = wm * 64 + i * 16 + l15;
            if constexpr (AF32) {
                const float* ap = (const float*)AsmRaw + r * 32 + quad * 8;
                f32x4 lo = *(const f32x4*)ap;
                f32x4 hi = *(const f32x4*)(ap + 4);
                bf16x8 v;
                v[0] = f2bf_rne(lo[0]); v[1] = f2bf_rne(lo[1]);
                v[2] = f2bf_rne(lo[2]); v[3] = f2bf_rne(lo[3]);
                v[4] = f2bf_rne(hi[0]); v[5] = f2bf_rne(hi[1]);
                v[6] = f2bf_rne(hi[2]); v[7] = f2bf_rne(hi[3]);
                afr[i] = v;
            } else {
                afr[i] = *(const bf16x8*)((const __hip_bfloat16*)AsmRaw + r * 32 + quad * 8);
            }
        }
#pragma unroll
        for (int j = 0; j < 4; j++) {
            int r = wn * 64 + j * 16 + l15;
            bfr[j] = *(const bf16x8*)((const __hip_bfloat16*)BsmRaw + r * 32 + quad * 8);
        }
#pragma unroll
        for (int i = 0; i < 4; i++)
#pragma unroll
            for (int j = 0; j < 4; j++)
                acc[i][j] = __builtin_amdgcn_mfma_f32_16x16x32_bf16(afr[i], bfr[j], acc[i][j], 0, 0, 0);
        __syncthreads();
    }

    float wa_j[4], dp_j[4];
#pragma unroll
    for (int j = 0; j < 4; j++) {
        int c = col0 + wn * 64 + j * 16 + l15;
        wa_j[j] = Wa[c];
        dp_j[j] = decp[b * K_SZ + c];
    }
    const int slotIdx = colBlk * 2 + wn;
#pragma unroll
    for (int i = 0; i < 4; i++) {
#pragma unroll
        for (int r = 0; r < 4; r++) {
            float tsum = 0.f;
#pragma unroll
            for (int j = 0; j < 4; j++)
                tsum += wa_j[j] * fast_tanh(acc[i][j][r] + dp_j[j]);
#pragma unroll
            for (int off = 1; off < 16; off <<= 1) tsum += __shfl_xor(tsum, off, 64);
            if (l15 == 0) {
                int m = row0 + wm * 64 + i * 16 + quad * 4 + r;
                sp[(size_t)slotIdx * M_SZ + m] = tsum;
            }
        }
    }
}

// ---- softmax over S per batch row (reduces the 16 partial slots) -----------

__global__ __launch_bounds__(256) void softmax_k(
    const float* __restrict__ sp, float* __restrict__ attn) {
    int b = blockIdx.x;
    int t = threadIdx.x;
    __shared__ float wred[4];
    __shared__ float wred2[4];
    float sc[8];
    float mx = -1e30f;
#pragma unroll
    for (int u = 0; u < 8; u++) {
        int m = b * S_SZ + t + u * 256;
        float v = 0.f;
#pragma unroll
        for (int c = 0; c < 16; c++) v += sp[(size_t)c * M_SZ + m];
        sc[u] = v;
        mx = fmaxf(mx, v);
    }
#pragma unroll
    for (int off = 1; off < 64; off <<= 1) mx = fmaxf(mx, __shfl_xor(mx, off, 64));
    if ((t & 63) == 0) wred[t >> 6] = mx;
    __syncthreads();
    mx = fmaxf(fmaxf(wred[0], wred[1]), fmaxf(wred[2], wred[3]));
    float lsum = 0.f;
#pragma unroll
    for (int u = 0; u < 8; u++) { sc[u] = expf(sc[u] - mx); lsum += sc[u]; }
#pragma unroll
    for (int off = 1; off < 64; off <<= 1) lsum += __shfl_xor(lsum, off, 64);
    if ((t & 63) == 0) wred2[t >> 6] = lsum;
    __syncthreads();
    float inv = 1.f / (wred2[0] + wred2[1] + wred2[2] + wred2[3]);
#pragma unroll
    for (int u = 0; u < 8; u++) attn[b * S_SZ + t + u * 256] = sc[u] * inv;
}

// ---- context partials: cp[c][b][h] = sum_{s in chunk c} attn[b,s]*enc[b,s,h]

template <bool BF16E>
__global__ __launch_bounds__(256) void ctx_part_k(
    const float* __restrict__ attn, const void* __restrict__ encp,
    float* __restrict__ cp) {
    int b = blockIdx.x >> 5;
    int c = blockIdx.x & 31;
    int t = threadIdx.x;
    __shared__ float wloc[64];
    if (t < 64) wloc[t] = attn[b * S_SZ + c * 64 + t];
    __syncthreads();
    float4 acc = {0.f, 0.f, 0.f, 0.f};
    if constexpr (BF16E) {
        const ushort4* ep = (const ushort4*)((const __hip_bfloat16*)encp +
                              ((size_t)b * S_SZ + (size_t)c * 64) * H_SZ);
#pragma unroll 8
        for (int s = 0; s < 64; s++) {
            float w = wloc[s];
            ushort4 v = ep[s * 256 + t];
            acc.x += w * bf2f(v.x); acc.y += w * bf2f(v.y);
            acc.z += w * bf2f(v.z); acc.w += w * bf2f(v.w);
        }
    } else {
        const float4* ep = (const float4*)((const float*)encp +
                              ((size_t)b * S_SZ + (size_t)c * 64) * H_SZ);
#pragma unroll 8
        for (int s = 0; s < 64; s++) {
            float w = wloc[s];
            float4 v = ep[s * 256 + t];
            acc.x += w * v.x; acc.y += w * v.y;
            acc.z += w * v.z; acc.w += w * v.w;
        }
    }
    ((float4*)(cp + ((size_t)c * B_SZ + b) * H_SZ))[t] = acc;
}

__global__ void ctx_red_k(const float* __restrict__ cp, float* __restrict__ out) {
    int i = blockIdx.x * blockDim.x + threadIdx.x;   // 0..32767
    float s = 0.f;
#pragma unroll
    for (int c = 0; c < 32; c++) s += cp[(size_t)c * (B_SZ * H_SZ) + i];
    out[i] = s;
}

// ---- launch -----------------------------------------------------------------

extern "C" void kernel_launch(void* const* d_in, const int* in_sizes, int n_in,
                              void* d_out, int out_size, void* d_ws, size_t ws_size,
                              hipStream_t stream) {
    const float* dec  = (const float*)d_in[0];
    const float* enc  = (const float*)d_in[1];
    const float* Wa_w = (const float*)d_in[2];
    // d_in[3] = Wa_b: softmax is shift-invariant, scalar bias cancels exactly.
    const float* Wb_w = (const float*)d_in[4];
    const float* Wb_b = (const float*)d_in[5];
    const float* Wc_w = (const float*)d_in[6];
    const float* Wc_b = (const float*)d_in[7];
    float* out = (float*)d_out;

    char* ws = (char*)d_ws;
    size_t off = 0;
    auto alloc = [&](size_t bytes) -> void* {
        void* p = ws + off;
        off += (bytes + 255) & ~(size_t)255;
        return p;
    };
    __hip_bfloat16* wc_bf = (__hip_bfloat16*)alloc((size_t)K_SZ * H_SZ * 2);
    float* dp     = (float*)alloc((size_t)B_SZ * K_SZ * 4);
    float* spart  = (float*)alloc((size_t)16 * M_SZ * 4);
    float* attn   = (float*)alloc((size_t)B_SZ * S_SZ * 4);
    float* cpart  = (float*)alloc((size_t)32 * B_SZ * H_SZ * 4);
    __hip_bfloat16* enc_bf = (__hip_bfloat16*)alloc((size_t)M_SZ * H_SZ * 2);
    const bool useBf16A = (off <= ws_size);   // ws_size-dependent only: same every call

    cvt_bf16_k<<<512, 256, 0, stream>>>(Wc_w, wc_bf, K_SZ * H_SZ / 8);
    if (useBf16A)
        cvt_bf16_k<<<8192, 256, 0, stream>>>(enc, enc_bf, M_SZ * H_SZ / 8);
    decproj_k<<<8192, 256, 0, stream>>>(dec, Wb_w, Wb_b, Wc_b, dp);
    if (useBf16A)
        gemm256_scores_k<<<(M_SZ / 256) * (K_SZ / 256), 512, 0, stream>>>(enc_bf, wc_bf, dp, Wa_w, spart);
    else
        gemm_scores_k<true><<<(M_SZ / 128) * 8, 256, 0, stream>>>(enc, wc_bf, dp, Wa_w, spart);
    softmax_k<<<B_SZ, 256, 0, stream>>>(spart, attn);
    if (useBf16A)
        ctx_part_k<true><<<B_SZ * 32, 256, 0, stream>>>(attn, enc_bf, cpart);
    else
        ctx_part_k<false><<<B_SZ * 32, 256, 0, stream>>>(attn, enc, cpart);
    ctx_red_k<<<128, 256, 0, stream>>>(cpart, out);
}

// Round 4
// 565.690 us; speedup vs baseline: 1.0236x; 1.0236x over previous
//
#include <hip/hip_runtime.h>
#include <hip/hip_bf16.h>
#include <stdint.h>

#define B_SZ 32
#define S_SZ 2048
#define H_SZ 1024
#define K_SZ 1024
#define M_SZ (B_SZ * S_SZ)   // 65536 rows of the big GEMM

typedef __attribute__((ext_vector_type(8))) short bf16x8;   // 8 bf16 = 4 VGPRs (MFMA A/B frag)
typedef __attribute__((ext_vector_type(4))) float f32x4;    // MFMA C/D frag

// ---- helpers ----------------------------------------------------------------

__device__ __forceinline__ short f2bf_rne(float f) {
    uint32_t u = __builtin_bit_cast(uint32_t, f);
    u += 0x7fffu + ((u >> 16) & 1u);   // round-to-nearest-even
    return (short)(u >> 16);
}

__device__ __forceinline__ float bf2f(unsigned short u) {
    return __builtin_bit_cast(float, (uint32_t)u << 16);
}

__device__ __forceinline__ float fast_tanh(float x) {
    // tanh(x) = 1 - 2/(exp(2x)+1); exact limits at +-inf, ~1e-6 rel err.
    float ex = __expf(2.0f * x);
    return 1.0f - 2.0f / (ex + 1.0f);
}

// ============================================================================
// fused prologue: (a) cvt Wc -> bf16 (+ zero `out` for the atomic ctx kernel),
// (b) cvt enc -> bf16, (c) dec_proj. Three independent jobs, one launch —
// branch by block range (wave-uniform, no divergence cost).
// ============================================================================

__global__ __launch_bounds__(256) void fused_pre_k(
    const float* __restrict__ Wc, __hip_bfloat16* __restrict__ wc_bf,
    const float* __restrict__ enc, __hip_bfloat16* __restrict__ enc_bf,
    int encB,                                   // 8192 (bf16 path) or 0 (fallback)
    const float* __restrict__ ds, const float* __restrict__ Wb,
    const float* __restrict__ Wb_b, const float* __restrict__ Wc_b,
    float* __restrict__ dp, float* __restrict__ out)
{
    const int blk = blockIdx.x;
    const int t = threadIdx.x;
    if (blk < 512) {
        // ---- cvt Wc: exactly 512*256 items of 8 elems ----
        int i = blk * 256 + t;
        const float4* p = (const float4*)Wc + (size_t)i * 2;
        float4 a = p[0], b = p[1];
        bf16x8 r;
        r[0] = f2bf_rne(a.x); r[1] = f2bf_rne(a.y);
        r[2] = f2bf_rne(a.z); r[3] = f2bf_rne(a.w);
        r[4] = f2bf_rne(b.x); r[5] = f2bf_rne(b.y);
        r[6] = f2bf_rne(b.z); r[7] = f2bf_rne(b.w);
        ((bf16x8*)wc_bf)[i] = r;
        // first 32 blocks also zero `out` (32*256 float4 = 32768 floats)
        if (blk < 32) ((float4*)out)[blk * 256 + t] = float4{0.f, 0.f, 0.f, 0.f};
    } else if (blk < 512 + encB) {
        // ---- cvt enc: grid-stride over M*H/8 items ----
        int idx = (blk - 512) * 256 + t;
        int stride = encB * 256;
        for (int i = idx; i < M_SZ * H_SZ / 8; i += stride) {
            const float4* p = (const float4*)enc + (size_t)i * 2;
            float4 a = p[0], b = p[1];
            bf16x8 r;
            r[0] = f2bf_rne(a.x); r[1] = f2bf_rne(a.y);
            r[2] = f2bf_rne(a.z); r[3] = f2bf_rne(a.w);
            r[4] = f2bf_rne(b.x); r[5] = f2bf_rne(b.y);
            r[6] = f2bf_rne(b.z); r[7] = f2bf_rne(b.w);
            ((bf16x8*)enc_bf)[i] = r;
        }
    } else {
        // ---- dec_proj[b][k] = dot(dec[b,:], Wb[k,:]) + Wb_b[k] + Wc_b[k] ----
        int g = (blk - 512 - encB) * 4 + (t >> 6);   // wave id = output id
        int lane = t & 63;
        int b = g >> 10;
        int k = g & 1023;
        const float4* wrow = (const float4*)(Wb + (size_t)k * H_SZ);
        const float4* xrow = (const float4*)(ds + (size_t)b * H_SZ);
        float sum = 0.f;
#pragma unroll
        for (int it = 0; it < 4; it++) {
            float4 w = wrow[lane + it * 64];
            float4 x = xrow[lane + it * 64];
            sum += w.x * x.x + w.y * x.y + w.z * x.z + w.w * x.w;
        }
#pragma unroll
        for (int off = 1; off < 64; off <<= 1) sum += __shfl_xor(sum, off, 64);
        if (lane == 0) dp[g] = sum + Wb_b[k] + Wc_b[k];
    }
}

// ============================================================================
// 256x256-tile GEMM — R2 structure (compiler-scheduled counted lgkm waits,
// the 163-µs best) with HALF-TILE barrier regions: 2 barriers/tile instead
// of 4. Within a region the compiler freely interleaves next-subphase
// ds_reads with current MFMAs (counted lgkmcnt). lgkmcnt(0) BEFORE each
// barrier (post-MFMA, ~free) makes the staged-buffer overwrite race-free:
// every wave's reads on a region completed before any wave can issue the
// overwriting global_load_lds after the barrier.
// NO post-barrier lgkm drain (R3's regression: full LDS/MFMA serialization),
// NO sched_barrier (R1/m141 regression).
//
// Geometry: BM=BN=256, BK=64, 8 waves (2Mx4N), 512 thr, LDS 128 KiB (2 dbuf),
// 1 block/CU, 2 waves/SIMD (launch_bounds-pinned).
// Staging: half1 A0,A1(t+1)->Anxt; half2 B0,B1(t+2)->Bcur. 8 loads/tile/wave;
// end-of-tile vmcnt(4): oldest 8 (= A(t+1) + the previous tile's B(t+1))
// landed, B(t+2) in flight. The lgkm fence before the mid barrier keeps
// A-stage issue strictly before B-stage issue -> oldest-first accounting holds.
//
// LDS swizzle (T2, rule #21): byte L of a [.][64]bf16 row stored at
// L ^ ((row&7)<<4); gload_lds dest LINEAR, source inverse-swizzled, ds_read
// same involution. Verified: bank conflicts 1.68e7 -> 0.
// ============================================================================

__device__ __forceinline__ void stage2(const __hip_bfloat16* __restrict__ srcRowBase,
                                       unsigned char* ldsHt, int k0,
                                       size_t laneOff, int ldsLane) {
#pragma unroll
    for (int inst = 0; inst < 2; inst++) {
        const char* g = (const char*)srcRowBase + (size_t)k0 * 2 + laneOff +
                        (size_t)inst * (64 * H_SZ * 2);
        __builtin_amdgcn_global_load_lds(
            (const __attribute__((address_space(1))) void*)g,
            (__attribute__((address_space(3))) void*)(ldsHt + inst * 8192 + ldsLane),
            16, 0, 0);
    }
}

__device__ __forceinline__ void read_afr(bf16x8 (&afr)[2][2], const unsigned char* Abuf,
                                         int aRowB, int phOff, int kOff0, int kOff1) {
#pragma unroll
    for (int i = 0; i < 2; ++i) {
        afr[i][0] = *(const bf16x8*)(Abuf + aRowB + phOff + i * 2048 + kOff0);
        afr[i][1] = *(const bf16x8*)(Abuf + aRowB + phOff + i * 2048 + kOff1);
    }
}

__device__ __forceinline__ void read_bfr(bf16x8 (&bfr)[4][2], const unsigned char* Bbuf,
                                         int bRowB, int kOff0, int kOff1) {
#pragma unroll
    for (int n = 0; n < 4; ++n) {
        bfr[n][0] = *(const bf16x8*)(Bbuf + bRowB + n * 2048 + kOff0);
        bfr[n][1] = *(const bf16x8*)(Bbuf + bRowB + n * 2048 + kOff1);
    }
}

__device__ __forceinline__ void mfma_ph(f32x4 (&acc)[8][4], const bf16x8 (&afr)[2][2],
                                        const bf16x8 (&bfr)[4][2], int base) {
    __builtin_amdgcn_s_setprio(1);
#pragma unroll
    for (int i = 0; i < 2; ++i)
#pragma unroll
        for (int ks = 0; ks < 2; ++ks)
#pragma unroll
            for (int n = 0; n < 4; ++n)
                acc[base + i][n] = __builtin_amdgcn_mfma_f32_16x16x32_bf16(
                    afr[i][ks], bfr[n][ks], acc[base + i][n], 0, 0, 0);
    __builtin_amdgcn_s_setprio(0);
}

// VM: 4 = steady counted wait, 0 = drain (tile 14), -1 = none (last tile)
template <int VM, bool SA, bool SB>
__device__ __forceinline__ void tile_run(
    const __hip_bfloat16* __restrict__ AgR, const __hip_bfloat16* __restrict__ BgR,
    const unsigned char* Acur, unsigned char* BcurW, unsigned char* Anxt,
    int kA, int kB, size_t laneOff, int ldsLane,
    int aRowB, int bRowB, int kOff0, int kOff1,
    f32x4 (&acc)[8][4])
{
    bf16x8 bfr[4][2];   // B-frags for this tile live across all 4 phases
    read_bfr(bfr, BcurW, bRowB, kOff0, kOff1);
    // ---- half 1: phases 0,1 (one barrier region) ----
    {
        bf16x8 afr[2][2];
        read_afr(afr, Acur, aRowB, 0, kOff0, kOff1);
        if (SA) stage2(AgR, Anxt, kA, laneOff, ldsLane);
        mfma_ph(acc, afr, bfr, 0);
    }
    {
        bf16x8 afr[2][2];
        read_afr(afr, Acur, aRowB, 4096, kOff0, kOff1);
        if (SA) stage2(AgR + 128 * H_SZ, Anxt + 16384, kA, laneOff, ldsLane);
        mfma_ph(acc, afr, bfr, 2);
    }
    asm volatile("s_waitcnt lgkmcnt(0)" ::: "memory");   // all B/A reads done
    __builtin_amdgcn_s_barrier();                        // -> B buffer writable
    // ---- half 2: phases 2,3 ----
    {
        bf16x8 afr[2][2];
        read_afr(afr, Acur, aRowB, 8192, kOff0, kOff1);
        if (SB) stage2(BgR, BcurW, kB, laneOff, ldsLane);
        mfma_ph(acc, afr, bfr, 4);
    }
    {
        bf16x8 afr[2][2];
        read_afr(afr, Acur, aRowB, 12288, kOff0, kOff1);
        if (SB) stage2(BgR + 128 * H_SZ, BcurW + 16384, kB, laneOff, ldsLane);
        mfma_ph(acc, afr, bfr, 6);
    }
    if (VM == 4) asm volatile("s_waitcnt vmcnt(4)" ::: "memory");
    if (VM == 0) asm volatile("s_waitcnt vmcnt(0)" ::: "memory");
    asm volatile("s_waitcnt lgkmcnt(0)" ::: "memory");   // all A reads done
    __builtin_amdgcn_s_barrier();                        // -> A buffer writable
}

__global__ __launch_bounds__(512, 2) void gemm256_scores_k(
    const __hip_bfloat16* __restrict__ Ag, const __hip_bfloat16* __restrict__ Bg,
    const float* __restrict__ decp, const float* __restrict__ Wa,
    float* __restrict__ sp)
{
    __shared__ __align__(16) unsigned char lds[131072];
    const int t = threadIdx.x;
    const int wave = t >> 6, lane = t & 63;
    const int wr = wave >> 2, wc = wave & 3;     // 2x4 waves over 256x256
    const int quad = lane >> 4, l15 = lane & 15;

    // XCD swizzle: 1024 blocks = 256 rowBlks x 4 colBlks; a rowBlk's 4 colBlks
    // land on the same XCD at consecutive per-XCD slots -> A-panel L2 reuse.
    const int id = blockIdx.x;
    const int colBlk = (id >> 3) & 3;
    const int rowBlk = ((id >> 5) << 3) | (id & 7);
    const int row0 = rowBlk * 256, col0 = colBlk * 256;  // 256|2048: one batch

    const int swz = (l15 & 7) << 4;              // row&7 == l15&7 for all frags
    const int aRowB = (wr * 128 + l15) * 128;
    const int bRowB = (wc * 64 + l15) * 128;
    const int kOff0 = (quad * 16) ^ swz;
    const int kOff1 = (64 + quad * 16) ^ swz;

    // staging per-lane constants
    const size_t laneOff = (size_t)(t >> 3) * (H_SZ * 2) +
                           ((((t & 7) ^ ((t >> 3) & 7)) << 4));
    const int ldsLane = (t >> 6) << 10;
    const __hip_bfloat16* AgR = Ag + (size_t)row0 * H_SZ;
    const __hip_bfloat16* BgR = Bg + (size_t)col0 * H_SZ;

    f32x4 acc[8][4];
#pragma unroll
    for (int i = 0; i < 8; i++)
#pragma unroll
        for (int j = 0; j < 4; j++) acc[i][j] = f32x4{0.f, 0.f, 0.f, 0.f};

    unsigned char* A0l = lds;                    // buf0: A [0,32K) B [32K,64K)
    unsigned char* B0l = lds + 32768;
    unsigned char* A1l = lds + 65536;            // buf1: A [64K,96K) B [96K,128K)
    unsigned char* B1l = lds + 98304;

    // prologue: tile0 fully + tile1's B; vmcnt(4) leaves tile1's B in flight
    stage2(BgR,                B0l,          0, laneOff, ldsLane);
    stage2(BgR + 128 * H_SZ,   B0l + 16384,  0, laneOff, ldsLane);
    stage2(AgR,                A0l,          0, laneOff, ldsLane);
    stage2(AgR + 128 * H_SZ,   A0l + 16384,  0, laneOff, ldsLane);
    stage2(BgR,                B1l,         64, laneOff, ldsLane);
    stage2(BgR + 128 * H_SZ,   B1l + 16384, 64, laneOff, ldsLane);
    asm volatile("s_waitcnt vmcnt(4)" ::: "memory");
    __builtin_amdgcn_s_barrier();

    // 16 K-tiles of 64: steady tiles 0..13, then drain tiles 14 and 15
#pragma unroll 2
    for (int tt = 0; tt < 14; ++tt) {
        unsigned char* Ac = (tt & 1) ? A1l : A0l;
        unsigned char* Bc = (tt & 1) ? B1l : B0l;
        unsigned char* An = (tt & 1) ? A0l : A1l;
        tile_run<4, true, true>(AgR, BgR, Ac, Bc, An,
                                (tt + 1) * 64, (tt + 2) * 64, laneOff, ldsLane,
                                aRowB, bRowB, kOff0, kOff1, acc);
    }
    tile_run<0, true, false>(AgR, BgR, A0l, B0l, A1l,
                             15 * 64, 0, laneOff, ldsLane,
                             aRowB, bRowB, kOff0, kOff1, acc);
    tile_run<-1, false, false>(AgR, BgR, A1l, B1l, A0l,
                               0, 0, laneOff, ldsLane,
                               aRowB, bRowB, kOff0, kOff1, acc);

    // fused epilogue: partial_m = sum_n Wa[n]*tanh(C[m][n]+decp[b][n])
    const int b = row0 >> 11;
    float wa_j[4], dp_j[4];
#pragma unroll
    for (int n = 0; n < 4; ++n) {
        int c = col0 + wc * 64 + n * 16 + l15;
        wa_j[n] = Wa[c];
        dp_j[n] = decp[b * K_SZ + c];
    }
    const int slotIdx = colBlk * 4 + wc;   // 16 partial slots per row
#pragma unroll
    for (int m = 0; m < 8; ++m) {
#pragma unroll
        for (int r = 0; r < 4; ++r) {
            float tsum = 0.f;
#pragma unroll
            for (int n = 0; n < 4; ++n)
                tsum += wa_j[n] * fast_tanh(acc[m][n][r] + dp_j[n]);
            // C/D layout: row=(lane>>4)*4+reg, col=lane&15 -> reduce 16 cols
#pragma unroll
            for (int off = 1; off < 16; off <<= 1) tsum += __shfl_xor(tsum, off, 64);
            if (l15 == 0) {
                int mrow = row0 + wr * 128 + m * 16 + quad * 4 + r;
                sp[(size_t)slotIdx * M_SZ + mrow] = tsum;
            }
        }
    }
}

// ---- legacy 128x128 GEMM (fp32-A fallback when ws is small) ----------------

template <bool AF32>
__global__ __launch_bounds__(256) void gemm_scores_k(
    const void* __restrict__ Aptr, const __hip_bfloat16* __restrict__ Bw,
    const float* __restrict__ decp, const float* __restrict__ Wa,
    float* __restrict__ sp) {
    constexpr int ABYTES = AF32 ? 128 * 32 * 4 : 128 * 32 * 2;
    __shared__ __align__(16) unsigned char AsmRaw[ABYTES];
    __shared__ __align__(16) unsigned char BsmRaw[128 * 32 * 2];

    const int t = threadIdx.x;
    const int wave = t >> 6;
    const int lane = t & 63;
    const int wm = wave >> 1, wn = wave & 1;
    const int quad = lane >> 4;
    const int l15 = lane & 15;

    const int id = blockIdx.x;
    const int colBlk = (id >> 3) & 7;
    const int rowBlk = ((id >> 6) << 3) | (id & 7);
    const int row0 = rowBlk * 128;
    const int col0 = colBlk * 128;
    const int b = row0 >> 11;

    f32x4 acc[4][4];
#pragma unroll
    for (int i = 0; i < 4; i++)
#pragma unroll
        for (int j = 0; j < 4; j++) acc[i][j] = f32x4{0.f, 0.f, 0.f, 0.f};

    const __hip_bfloat16* Ab = (const __hip_bfloat16*)Aptr;
    const float* Af = (const float*)Aptr;

    for (int k0 = 0; k0 < H_SZ; k0 += 32) {
        if constexpr (AF32) {
#pragma unroll
            for (int inst = 0; inst < 4; inst++) {
                int slot = inst * 256 + t;
                int r = slot >> 3, c4 = slot & 7;
                const float* g = Af + (size_t)(row0 + r) * H_SZ + k0 + c4 * 4;
                __builtin_amdgcn_global_load_lds(
                    (const __attribute__((address_space(1))) void*)g,
                    (__attribute__((address_space(3))) void*)(AsmRaw + inst * 4096 + wave * 1024),
                    16, 0, 0);
            }
        } else {
#pragma unroll
            for (int inst = 0; inst < 2; inst++) {
                int slot = inst * 256 + t;
                int r = slot >> 2, c8 = slot & 3;
                const __hip_bfloat16* g = Ab + (size_t)(row0 + r) * H_SZ + k0 + c8 * 8;
                __builtin_amdgcn_global_load_lds(
                    (const __attribute__((address_space(1))) void*)g,
                    (__attribute__((address_space(3))) void*)(AsmRaw + inst * 4096 + wave * 1024),
                    16, 0, 0);
            }
        }
#pragma unroll
        for (int inst = 0; inst < 2; inst++) {
            int slot = inst * 256 + t;
            int r = slot >> 2, c8 = slot & 3;
            const __hip_bfloat16* g = Bw + (size_t)(col0 + r) * H_SZ + k0 + c8 * 8;
            __builtin_amdgcn_global_load_lds(
                (const __attribute__((address_space(1))) void*)g,
                (__attribute__((address_space(3))) void*)(BsmRaw + inst * 4096 + wave * 1024),
                16, 0, 0);
        }
        __syncthreads();

        bf16x8 afr[4], bfr[4];
#pragma unroll
        for (int i = 0; i < 4; i++) {
            int r = wm * 64 + i * 16 + l15;
            if constexpr (AF32) {
                const float* ap = (const float*)AsmRaw + r * 32 + quad * 8;
                f32x4 lo = *(const f32x4*)ap;
                f32x4 hi = *(const f32x4*)(ap + 4);
                bf16x8 v;
                v[0] = f2bf_rne(lo[0]); v[1] = f2bf_rne(lo[1]);
                v[2] = f2bf_rne(lo[2]); v[3] = f2bf_rne(lo[3]);
                v[4] = f2bf_rne(hi[0]); v[5] = f2bf_rne(hi[1]);
                v[6] = f2bf_rne(hi[2]); v[7] = f2bf_rne(hi[3]);
                afr[i] = v;
            } else {
                afr[i] = *(const bf16x8*)((const __hip_bfloat16*)AsmRaw + r * 32 + quad * 8);
            }
        }
#pragma unroll
        for (int j = 0; j < 4; j++) {
            int r = wn * 64 + j * 16 + l15;
            bfr[j] = *(const bf16x8*)((const __hip_bfloat16*)BsmRaw + r * 32 + quad * 8);
        }
#pragma unroll
        for (int i = 0; i < 4; i++)
#pragma unroll
            for (int j = 0; j < 4; j++)
                acc[i][j] = __builtin_amdgcn_mfma_f32_16x16x32_bf16(afr[i], bfr[j], acc[i][j], 0, 0, 0);
        __syncthreads();
    }

    float wa_j[4], dp_j[4];
#pragma unroll
    for (int j = 0; j < 4; j++) {
        int c = col0 + wn * 64 + j * 16 + l15;
        wa_j[j] = Wa[c];
        dp_j[j] = decp[b * K_SZ + c];
    }
    const int slotIdx = colBlk * 2 + wn;
#pragma unroll
    for (int i = 0; i < 4; i++) {
#pragma unroll
        for (int r = 0; r < 4; r++) {
            float tsum = 0.f;
#pragma unroll
            for (int j = 0; j < 4; j++)
                tsum += wa_j[j] * fast_tanh(acc[i][j][r] + dp_j[j]);
#pragma unroll
            for (int off = 1; off < 16; off <<= 1) tsum += __shfl_xor(tsum, off, 64);
            if (l15 == 0) {
                int m = row0 + wm * 64 + i * 16 + quad * 4 + r;
                sp[(size_t)slotIdx * M_SZ + m] = tsum;
            }
        }
    }
}

// ---- softmax over S per batch row (reduces the 16 partial slots) -----------

__global__ __launch_bounds__(256) void softmax_k(
    const float* __restrict__ sp, float* __restrict__ attn) {
    int b = blockIdx.x;
    int t = threadIdx.x;
    __shared__ float wred[4];
    __shared__ float wred2[4];
    float sc[8];
    float mx = -1e30f;
#pragma unroll
    for (int u = 0; u < 8; u++) {
        int m = b * S_SZ + t + u * 256;
        float v = 0.f;
#pragma unroll
        for (int c = 0; c < 16; c++) v += sp[(size_t)c * M_SZ + m];
        sc[u] = v;
        mx = fmaxf(mx, v);
    }
#pragma unroll
    for (int off = 1; off < 64; off <<= 1) mx = fmaxf(mx, __shfl_xor(mx, off, 64));
    if ((t & 63) == 0) wred[t >> 6] = mx;
    __syncthreads();
    mx = fmaxf(fmaxf(wred[0], wred[1]), fmaxf(wred[2], wred[3]));
    float lsum = 0.f;
#pragma unroll
    for (int u = 0; u < 8; u++) { sc[u] = expf(sc[u] - mx); lsum += sc[u]; }
#pragma unroll
    for (int off = 1; off < 64; off <<= 1) lsum += __shfl_xor(lsum, off, 64);
    if ((t & 63) == 0) wred2[t >> 6] = lsum;
    __syncthreads();
    float inv = 1.f / (wred2[0] + wred2[1] + wred2[2] + wred2[3]);
#pragma unroll
    for (int u = 0; u < 8; u++) attn[b * S_SZ + t + u * 256] = sc[u] * inv;
}

// ---- fused context: out[b][h] += sum_{s in chunk} attn[b,s]*enc[b,s,h] ----
// One kernel replaces ctx_part + ctx_red: each block accumulates its 64-s
// chunk in registers, then ONE atomicAdd per output element (32-way over
// time; fp32 add commutes, rounding shift ~1e-6 << tolerance). `out` is
// zeroed by fused_pre_k.

__global__ __launch_bounds__(256) void ctx_atomic_k(
    const float* __restrict__ attn, const __hip_bfloat16* __restrict__ encp,
    float* __restrict__ out) {
    int b = blockIdx.x >> 5;
    int c = blockIdx.x & 31;
    int t = threadIdx.x;
    __shared__ float wloc[64];
    if (t < 64) wloc[t] = attn[b * S_SZ + c * 64 + t];
    __syncthreads();
    float4 acc = {0.f, 0.f, 0.f, 0.f};
    const ushort4* ep = (const ushort4*)(encp +
                          ((size_t)b * S_SZ + (size_t)c * 64) * H_SZ);
#pragma unroll 8
    for (int s = 0; s < 64; s++) {
        float w = wloc[s];
        ushort4 v = ep[s * 256 + t];
        acc.x += w * bf2f(v.x); acc.y += w * bf2f(v.y);
        acc.z += w * bf2f(v.z); acc.w += w * bf2f(v.w);
    }
    float* o = out + (size_t)b * H_SZ + t * 4;
    atomicAdd(o + 0, acc.x);
    atomicAdd(o + 1, acc.y);
    atomicAdd(o + 2, acc.z);
    atomicAdd(o + 3, acc.w);
}

// ---- legacy context path (fp32 fallback) -----------------------------------

__global__ __launch_bounds__(256) void ctx_part_k(
    const float* __restrict__ attn, const float* __restrict__ encp,
    float* __restrict__ cp) {
    int b = blockIdx.x >> 5;
    int c = blockIdx.x & 31;
    int t = threadIdx.x;
    __shared__ float wloc[64];
    if (t < 64) wloc[t] = attn[b * S_SZ + c * 64 + t];
    __syncthreads();
    float4 acc = {0.f, 0.f, 0.f, 0.f};
    const float4* ep = (const float4*)(encp +
                          ((size_t)b * S_SZ + (size_t)c * 64) * H_SZ);
#pragma unroll 8
    for (int s = 0; s < 64; s++) {
        float w = wloc[s];
        float4 v = ep[s * 256 + t];
        acc.x += w * v.x; acc.y += w * v.y;
        acc.z += w * v.z; acc.w += w * v.w;
    }
    ((float4*)(cp + ((size_t)c * B_SZ + b) * H_SZ))[t] = acc;
}

__global__ void ctx_red_k(const float* __restrict__ cp, float* __restrict__ out) {
    int i = blockIdx.x * blockDim.x + threadIdx.x;   // 0..32767
    float s = 0.f;
#pragma unroll
    for (int c = 0; c < 32; c++) s += cp[(size_t)c * (B_SZ * H_SZ) + i];
    out[i] = s;
}

// ---- launch -----------------------------------------------------------------

extern "C" void kernel_launch(void* const* d_in, const int* in_sizes, int n_in,
                              void* d_out, int out_size, void* d_ws, size_t ws_size,
                              hipStream_t stream) {
    const float* dec  = (const float*)d_in[0];
    const float* enc  = (const float*)d_in[1];
    const float* Wa_w = (const float*)d_in[2];
    // d_in[3] = Wa_b: softmax is shift-invariant, scalar bias cancels exactly.
    const float* Wb_w = (const float*)d_in[4];
    const float* Wb_b = (const float*)d_in[5];
    const float* Wc_w = (const float*)d_in[6];
    const float* Wc_b = (const float*)d_in[7];
    float* out = (float*)d_out;

    char* ws = (char*)d_ws;
    size_t off = 0;
    auto alloc = [&](size_t bytes) -> void* {
        void* p = ws + off;
        off += (bytes + 255) & ~(size_t)255;
        return p;
    };
    __hip_bfloat16* wc_bf = (__hip_bfloat16*)alloc((size_t)K_SZ * H_SZ * 2);
    float* dp     = (float*)alloc((size_t)B_SZ * K_SZ * 4);
    float* spart  = (float*)alloc((size_t)16 * M_SZ * 4);
    float* attn   = (float*)alloc((size_t)B_SZ * S_SZ * 4);
    float* cpart  = (float*)alloc((size_t)32 * B_SZ * H_SZ * 4);
    __hip_bfloat16* enc_bf = (__hip_bfloat16*)alloc((size_t)M_SZ * H_SZ * 2);
    const bool useBf16A = (off <= ws_size);   // ws_size-dependent only: same every call

    const int encB = useBf16A ? 8192 : 0;
    fused_pre_k<<<512 + encB + 8192, 256, 0, stream>>>(
        Wc_w, wc_bf, enc, enc_bf, encB, dec, Wb_w, Wb_b, Wc_b, dp, out);
    if (useBf16A)
        gemm256_scores_k<<<(M_SZ / 256) * (K_SZ / 256), 512, 0, stream>>>(enc_bf, wc_bf, dp, Wa_w, spart);
    else
        gemm_scores_k<true><<<(M_SZ / 128) * 8, 256, 0, stream>>>(enc, wc_bf, dp, Wa_w, spart);
    softmax_k<<<B_SZ, 256, 0, stream>>>(spart, attn);
    if (useBf16A) {
        ctx_atomic_k<<<B_SZ * 32, 256, 0, stream>>>(attn, enc_bf, out);
    } else {
        ctx_part_k<<<B_SZ * 32, 256, 0, stream>>>(attn, enc, cpart);
        ctx_red_k<<<128, 256, 0, stream>>>(cpart, out);
    }
}